// Round 1
// baseline (424.655 us; speedup 1.0000x reference)
//
#include <hip/hip_runtime.h>
#include <hip/hip_bf16.h>
#include <math.h>

// Problem constants (fixed by the reference)
constexpr int Bn = 32768;   // batch
constexpr int Dn = 256;     // embedding dim
constexpr int Cn = 2048;    // classes
#define EPSF 1e-12f
#define INFF __builtin_inff()

typedef __bf16 bf16x8 __attribute__((ext_vector_type(8)));
typedef float  f32x4  __attribute__((ext_vector_type(4)));

// ---------------- K1: row inv-norms ----------------
// grid 512 x 256 threads; each wave handles 16 rows, lane reads float4.
__global__ __launch_bounds__(256) void k_norm(const float* __restrict__ feat,
                                              float* __restrict__ inv_norm) {
    const int wave = threadIdx.x >> 6, lane = threadIdx.x & 63;
    const int base = (blockIdx.x * 4 + wave) * 16;
    for (int s = 0; s < 16; ++s) {
        const int row = base + s;
        const float4 v = ((const float4*)(feat + (size_t)row * Dn))[lane];
        float ss = v.x * v.x + v.y * v.y + v.z * v.z + v.w * v.w;
        #pragma unroll
        for (int off = 1; off < 64; off <<= 1) ss += __shfl_xor(ss, off, 64);
        if (lane == 0) inv_norm[row] = 1.0f / fmaxf(sqrtf(ss), EPSF);
    }
}

// ---------------- K2: segment sums + counts (fp32 atomics) ----------------
// one thread per (sample, 4-dim group): B*64 threads.
__global__ __launch_bounds__(256) void k_segsum(const float* __restrict__ feat,
                                                const int* __restrict__ labels,
                                                const float* __restrict__ inv_norm,
                                                float* __restrict__ sums,
                                                float* __restrict__ counts) {
    const int idx = blockIdx.x * 256 + threadIdx.x;
    const int s = idx >> 6, g = idx & 63;
    const int l = labels[s];
    const float inv = inv_norm[s];
    const float4 v = ((const float4*)(feat + (size_t)s * Dn))[g];
    float* dst = sums + (size_t)l * Dn + g * 4;
    atomicAdd(dst + 0, v.x * inv);
    atomicAdd(dst + 1, v.y * inv);
    atomicAdd(dst + 2, v.z * inv);
    atomicAdd(dst + 3, v.w * inv);
    if (g == 0) atomicAdd(counts + l, 1.0f);
}

// ---------------- K3: centroids (bf16) + cn2 (+inf sentinel for empty) ----
// grid Cn/4 x 256; one wave per class, lane handles 4 dims.
__global__ __launch_bounds__(256) void k_centroid(const float* __restrict__ sums,
                                                  const float* __restrict__ counts,
                                                  __bf16* __restrict__ cent_bf,
                                                  float* __restrict__ cn2x) {
    const int wave = threadIdx.x >> 6, lane = threadIdx.x & 63;
    const int c = blockIdx.x * 4 + wave;
    const float cnt = counts[c];
    const float inv = 1.0f / fmaxf(cnt, 1.0f);
    const float4 v = ((const float4*)(sums + (size_t)c * Dn))[lane];
    const float cx = v.x * inv, cy = v.y * inv, cz = v.z * inv, cw = v.w * inv;
    __bf16* dst = cent_bf + (size_t)c * Dn + lane * 4;
    dst[0] = (__bf16)cx; dst[1] = (__bf16)cy; dst[2] = (__bf16)cz; dst[3] = (__bf16)cw;
    float ss = cx * cx + cy * cy + cz * cz + cw * cw;
    #pragma unroll
    for (int off = 1; off < 64; off <<= 1) ss += __shfl_xor(ss, off, 64);
    if (lane == 0) cn2x[c] = (cnt > 0.0f) ? ss : INFF;
}

// ---------------- K4: fused bf16-MFMA dot + masked min over classes -------
// grid (Bn/128, 2); block 256 = 4 waves; wave owns 32 samples (2 MFMA tiles);
// blockIdx.y splits the class range in half; partial mins land in minval[y][B].
__global__ __launch_bounds__(256) void k_main(const float* __restrict__ feat,
                                              const int* __restrict__ labels,
                                              const float* __restrict__ inv_norm,
                                              const __bf16* __restrict__ cent_bf,
                                              const float* __restrict__ cn2x,
                                              float* __restrict__ minval) {
    const int lane = threadIdx.x & 63;
    const int wave = threadIdx.x >> 6;
    const int m16 = lane & 15;
    const int quad = lane >> 4;
    const int sbase = blockIdx.x * 128 + wave * 32;
    const int cls_begin = blockIdx.y * (Cn / 2);
    const int cls_end   = cls_begin + (Cn / 2);

    // A fragments for 2 sample tiles: a[p][t], lane holds f[sbase+16p+m16][32t+8*quad .. +7]
    bf16x8 a[2][8];
    #pragma unroll
    for (int p = 0; p < 2; ++p) {
        const int row = sbase + p * 16 + m16;
        const float inv = inv_norm[row];
        const float* fr = feat + (size_t)row * Dn;
        #pragma unroll
        for (int t = 0; t < 8; ++t) {
            const float4* p4 = (const float4*)(fr + t * 32 + quad * 8);
            const float4 v0 = p4[0], v1 = p4[1];
            bf16x8 af;
            af[0] = (__bf16)(v0.x * inv); af[1] = (__bf16)(v0.y * inv);
            af[2] = (__bf16)(v0.z * inv); af[3] = (__bf16)(v0.w * inv);
            af[4] = (__bf16)(v1.x * inv); af[5] = (__bf16)(v1.y * inv);
            af[6] = (__bf16)(v1.z * inv); af[7] = (__bf16)(v1.w * inv);
            a[p][t] = af;
        }
    }
    // labels of the 4 output rows each reg covers (C/D layout: row = quad*4 + r)
    int lab0[4], lab1[4];
    #pragma unroll
    for (int r = 0; r < 4; ++r) {
        lab0[r] = labels[sbase + quad * 4 + r];
        lab1[r] = labels[sbase + 16 + quad * 4 + r];
    }

    float rm0[4] = {INFF, INFF, INFF, INFF};
    float rm1[4] = {INFF, INFF, INFF, INFF};

    for (int c0 = cls_begin; c0 < cls_end; c0 += 16) {
        const int crow = c0 + m16;   // class this lane's B-frag / output column covers
        const __bf16* cr = cent_bf + (size_t)crow * Dn;
        bf16x8 b[8];
        #pragma unroll
        for (int t = 0; t < 8; ++t)
            b[t] = *(const bf16x8*)(cr + t * 32 + quad * 8);
        f32x4 acc0 = {0.f, 0.f, 0.f, 0.f};
        f32x4 acc1 = {0.f, 0.f, 0.f, 0.f};
        #pragma unroll
        for (int t = 0; t < 8; ++t) {
            acc0 = __builtin_amdgcn_mfma_f32_16x16x32_bf16(a[0][t], b[t], acc0, 0, 0, 0);
            acc1 = __builtin_amdgcn_mfma_f32_16x16x32_bf16(a[1][t], b[t], acc1, 0, 0, 0);
        }
        const float cn2v = cn2x[crow];   // +inf for empty classes
        #pragma unroll
        for (int r = 0; r < 4; ++r) {
            const float s0 = (crow == lab0[r]) ? INFF : cn2v - 2.0f * acc0[r];
            rm0[r] = fminf(rm0[r], s0);
            const float s1 = (crow == lab1[r]) ? INFF : cn2v - 2.0f * acc1[r];
            rm1[r] = fminf(rm1[r], s1);
        }
    }
    // min across the 16 lanes sharing a quad-row group
    #pragma unroll
    for (int off = 1; off < 16; off <<= 1) {
        #pragma unroll
        for (int r = 0; r < 4; ++r) {
            rm0[r] = fminf(rm0[r], __shfl_xor(rm0[r], off, 64));
            rm1[r] = fminf(rm1[r], __shfl_xor(rm1[r], off, 64));
        }
    }
    if (m16 == 0) {
        float* mv = minval + (size_t)blockIdx.y * Bn;
        #pragma unroll
        for (int r = 0; r < 4; ++r) {
            mv[sbase + quad * 4 + r]      = rm0[r];
            mv[sbase + 16 + quad * 4 + r] = rm1[r];
        }
    }
}

// ---------------- K5: d_p + softplus loss accumulation --------------------
// grid 512 x 256; wave per sample, loops 16 samples.
__global__ __launch_bounds__(256) void k_loss(const float* __restrict__ feat,
                                              const int* __restrict__ labels,
                                              const float* __restrict__ inv_norm,
                                              const float* __restrict__ sums,
                                              const float* __restrict__ counts,
                                              const float* __restrict__ minval,
                                              const int* __restrict__ epoch,
                                              float* __restrict__ accum) {
    const int wave = threadIdx.x >> 6, lane = threadIdx.x & 63;
    const int base = (blockIdx.x * 4 + wave) * 16;
    const float temp = fminf(0.3f + 0.02f * (float)(*epoch), 1.0f);
    float wsum = 0.0f, wcnt = 0.0f;
    for (int s = 0; s < 16; ++s) {
        const int i = base + s;
        const int l = labels[i];
        const float cnt = counts[l];
        const float inv = inv_norm[i];
        const float4 fv = ((const float4*)(feat + (size_t)i * Dn))[lane];
        const float4 sv = ((const float4*)(sums + (size_t)l * Dn))[lane];
        const float idenom = 1.0f / fmaxf(cnt - 1.0f, 1.0f);
        const float fx = fv.x * inv, fy = fv.y * inv, fz = fv.z * inv, fw = fv.w * inv;
        // c_p = (sum - f)/denom ; diff = f - c_p
        const float dx = fx - (sv.x - fx) * idenom;
        const float dy = fy - (sv.y - fy) * idenom;
        const float dz = fz - (sv.z - fz) * idenom;
        const float dw = fw - (sv.w - fw) * idenom;
        float ss = dx * dx + dy * dy + dz * dz + dw * dw;
        #pragma unroll
        for (int off = 1; off < 64; off <<= 1) ss += __shfl_xor(ss, off, 64);
        const float d_p = sqrtf(ss + EPSF);
        const float m = fminf(minval[i], minval[Bn + i]);
        const bool finite = (m < 1e37f);
        const float d_n = finite ? sqrtf(fmaxf(1.0f + m, EPSF)) : 0.0f;
        const bool valid = (cnt > 1.0f) && finite;
        if (valid) {
            const float x = (d_p - d_n) / temp;
            wsum += fmaxf(x, 0.0f) + log1pf(expf(-fabsf(x)));   // softplus
            wcnt += 1.0f;
        }
    }
    if (lane == 0) {
        atomicAdd(&accum[0], wsum);
        atomicAdd(&accum[1], wcnt);
    }
}

// ---------------- K6: finalize --------------------------------------------
__global__ void k_final(const float* __restrict__ accum, float* __restrict__ out) {
    const float s = accum[0], c = accum[1];
    out[0] = (c > 0.0f) ? (s / fmaxf(c, 1.0f)) : 0.0f;   // WEIGHT = 1.0
}

// ---------------- launch ---------------------------------------------------
extern "C" void kernel_launch(void* const* d_in, const int* in_sizes, int n_in,
                              void* d_out, int out_size, void* d_ws, size_t ws_size,
                              hipStream_t stream) {
    const float* feat  = (const float*)d_in[0];
    const int* labels  = (const int*)d_in[1];
    const int* epoch   = (const int*)d_in[2];
    float* out = (float*)d_out;
    char* ws = (char*)d_ws;

    // workspace layout (bytes)
    float*  sums     = (float*)(ws + 0);              // Cn*Dn*4 = 2 MiB
    __bf16* cent_bf  = (__bf16*)(ws + 2097152);       // Cn*Dn*2 = 1 MiB
    float*  inv_norm = (float*)(ws + 3145728);        // Bn*4    = 128 KiB
    float*  counts   = (float*)(ws + 3276800);        // Cn*4    = 8 KiB
    float*  cn2x     = (float*)(ws + 3284992);        // Cn*4    = 8 KiB
    float*  minval   = (float*)(ws + 3293184);        // 2*Bn*4  = 256 KiB
    float*  accum    = (float*)(ws + 3555328);        // 2*4

    (void)hipMemsetAsync(sums,   0, (size_t)Cn * Dn * sizeof(float), stream);
    (void)hipMemsetAsync(counts, 0, (size_t)Cn * sizeof(float), stream);
    (void)hipMemsetAsync(accum,  0, 2 * sizeof(float), stream);

    k_norm<<<Bn / 64, 256, 0, stream>>>(feat, inv_norm);
    k_segsum<<<(Bn * 64) / 256, 256, 0, stream>>>(feat, labels, inv_norm, sums, counts);
    k_centroid<<<Cn / 4, 256, 0, stream>>>(sums, counts, cent_bf, cn2x);
    dim3 g4(Bn / 128, 2);
    k_main<<<g4, 256, 0, stream>>>(feat, labels, inv_norm, cent_bf, cn2x, minval);
    k_loss<<<Bn / 64, 256, 0, stream>>>(feat, labels, inv_norm, sums, counts, minval,
                                        epoch, accum);
    k_final<<<1, 1, 0, stream>>>(accum, out);
}

// Round 2
// 401.115 us; speedup vs baseline: 1.0587x; 1.0587x over previous
//
#include <hip/hip_runtime.h>
#include <hip/hip_bf16.h>
#include <math.h>

// Problem constants (fixed by the reference)
constexpr int Bn = 32768;   // batch
constexpr int Dn = 256;     // embedding dim
constexpr int Cn = 2048;    // classes
constexpr int NPART = 8;    // privatized segment-sum buffers
constexpr int NSPLIT = 8;   // class splits in k_main
#define EPSF 1e-12f
#define INFF __builtin_inff()

typedef __bf16 bf16x8 __attribute__((ext_vector_type(8)));
typedef __bf16 bf16x4 __attribute__((ext_vector_type(4)));
typedef float  f32x4  __attribute__((ext_vector_type(4)));

// ---------------- K1: fused normalize + privatized segment sums -----------
// one wave per sample; lane covers 4 dims. Writes inv_norm, bf16 normalized
// features, and atomically accumulates into sums_part[blockIdx&7].
__global__ __launch_bounds__(256) void k_prep(const float* __restrict__ feat,
                                              const int* __restrict__ labels,
                                              float* __restrict__ sums_part,
                                              float* __restrict__ counts,
                                              float* __restrict__ inv_norm,
                                              __bf16* __restrict__ fnorm) {
    const int wave = threadIdx.x >> 6, lane = threadIdx.x & 63;
    const int s = blockIdx.x * 4 + wave;
    const int l = labels[s];
    const float4 v = ((const float4*)(feat + (size_t)s * Dn))[lane];
    float ss = v.x * v.x + v.y * v.y + v.z * v.z + v.w * v.w;
    #pragma unroll
    for (int off = 1; off < 64; off <<= 1) ss += __shfl_xor(ss, off, 64);
    const float inv = 1.0f / fmaxf(sqrtf(ss), EPSF);
    if (lane == 0) {
        inv_norm[s] = inv;
        atomicAdd(counts + l, 1.0f);
    }
    const float fx = v.x * inv, fy = v.y * inv, fz = v.z * inv, fw = v.w * inv;
    bf16x4 bf; bf[0] = (__bf16)fx; bf[1] = (__bf16)fy; bf[2] = (__bf16)fz; bf[3] = (__bf16)fw;
    *(bf16x4*)(fnorm + (size_t)s * Dn + lane * 4) = bf;
    float* dst = sums_part + (size_t)(blockIdx.x & (NPART - 1)) * Cn * Dn
               + (size_t)l * Dn + lane * 4;
    atomicAdd(dst + 0, fx);
    atomicAdd(dst + 1, fy);
    atomicAdd(dst + 2, fz);
    atomicAdd(dst + 3, fw);
}

// ---------------- K2: reduce partials -> centroids (bf16) + cn2 + sums ----
// one wave per class; lane covers 4 dims.
__global__ __launch_bounds__(256) void k_centroid(const float* __restrict__ sums_part,
                                                  const float* __restrict__ counts,
                                                  float* __restrict__ sums_tot,
                                                  __bf16* __restrict__ cent_bf,
                                                  float* __restrict__ cn2x) {
    const int wave = threadIdx.x >> 6, lane = threadIdx.x & 63;
    const int c = blockIdx.x * 4 + wave;
    float4 acc = {0.f, 0.f, 0.f, 0.f};
    #pragma unroll
    for (int p = 0; p < NPART; ++p) {
        const float4 v = ((const float4*)(sums_part + (size_t)p * Cn * Dn
                                          + (size_t)c * Dn))[lane];
        acc.x += v.x; acc.y += v.y; acc.z += v.z; acc.w += v.w;
    }
    ((float4*)(sums_tot + (size_t)c * Dn))[lane] = acc;
    const float cnt = counts[c];
    const float inv = 1.0f / fmaxf(cnt, 1.0f);
    const float cx = acc.x * inv, cy = acc.y * inv, cz = acc.z * inv, cw = acc.w * inv;
    bf16x4 bf; bf[0] = (__bf16)cx; bf[1] = (__bf16)cy; bf[2] = (__bf16)cz; bf[3] = (__bf16)cw;
    *(bf16x4*)(cent_bf + (size_t)c * Dn + lane * 4) = bf;
    float ss = cx * cx + cy * cy + cz * cz + cw * cw;
    #pragma unroll
    for (int off = 1; off < 64; off <<= 1) ss += __shfl_xor(ss, off, 64);
    if (lane == 0) cn2x[c] = (cnt > 0.0f) ? ss : INFF;
}

// ---------------- K3: fused bf16-MFMA dot + masked min over classes -------
// grid (Bn/128, NSPLIT); block 256 = 4 waves; wave owns 32 samples (2 tiles);
// blockIdx.y picks a 256-class chunk; partial mins land in minval[y][B].
__global__ __launch_bounds__(256) void k_main(const __bf16* __restrict__ fnorm,
                                              const int* __restrict__ labels,
                                              const __bf16* __restrict__ cent_bf,
                                              const float* __restrict__ cn2x,
                                              float* __restrict__ minval) {
    const int lane = threadIdx.x & 63;
    const int wave = threadIdx.x >> 6;
    const int m16 = lane & 15;
    const int quad = lane >> 4;
    const int sbase = blockIdx.x * 128 + wave * 32;
    const int cls_begin = blockIdx.y * (Cn / NSPLIT);
    const int cls_end   = cls_begin + (Cn / NSPLIT);

    // A fragments: lane holds fnorm[sbase+16p+m16][32t+8*quad .. +7]
    bf16x8 a[2][8];
    #pragma unroll
    for (int p = 0; p < 2; ++p) {
        const __bf16* fr = fnorm + (size_t)(sbase + p * 16 + m16) * Dn;
        #pragma unroll
        for (int t = 0; t < 8; ++t)
            a[p][t] = *(const bf16x8*)(fr + t * 32 + quad * 8);
    }
    // labels of the 4 output rows each acc reg covers (C/D: row = quad*4 + r)
    int lab0[4], lab1[4];
    #pragma unroll
    for (int r = 0; r < 4; ++r) {
        lab0[r] = labels[sbase + quad * 4 + r];
        lab1[r] = labels[sbase + 16 + quad * 4 + r];
    }

    float rm0[4] = {INFF, INFF, INFF, INFF};
    float rm1[4] = {INFF, INFF, INFF, INFF};

    for (int c0 = cls_begin; c0 < cls_end; c0 += 16) {
        const int crow = c0 + m16;   // class this lane's output column covers
        const __bf16* cr = cent_bf + (size_t)crow * Dn;
        bf16x8 b[8];
        #pragma unroll
        for (int t = 0; t < 8; ++t)
            b[t] = *(const bf16x8*)(cr + t * 32 + quad * 8);
        f32x4 acc0 = {0.f, 0.f, 0.f, 0.f};
        f32x4 acc1 = {0.f, 0.f, 0.f, 0.f};
        #pragma unroll
        for (int t = 0; t < 8; ++t) {
            acc0 = __builtin_amdgcn_mfma_f32_16x16x32_bf16(a[0][t], b[t], acc0, 0, 0, 0);
            acc1 = __builtin_amdgcn_mfma_f32_16x16x32_bf16(a[1][t], b[t], acc1, 0, 0, 0);
        }
        const float cn2v = cn2x[crow];   // +inf for empty classes
        #pragma unroll
        for (int r = 0; r < 4; ++r) {
            const float s0 = (crow == lab0[r]) ? INFF : cn2v - 2.0f * acc0[r];
            rm0[r] = fminf(rm0[r], s0);
            const float s1 = (crow == lab1[r]) ? INFF : cn2v - 2.0f * acc1[r];
            rm1[r] = fminf(rm1[r], s1);
        }
    }
    // min across the 16 lanes of each output row-group
    #pragma unroll
    for (int off = 1; off < 16; off <<= 1) {
        #pragma unroll
        for (int r = 0; r < 4; ++r) {
            rm0[r] = fminf(rm0[r], __shfl_xor(rm0[r], off, 64));
            rm1[r] = fminf(rm1[r], __shfl_xor(rm1[r], off, 64));
        }
    }
    if (m16 == 0) {
        float* mv = minval + (size_t)blockIdx.y * Bn;
        #pragma unroll
        for (int r = 0; r < 4; ++r) {
            mv[sbase + quad * 4 + r]      = rm0[r];
            mv[sbase + 16 + quad * 4 + r] = rm1[r];
        }
    }
}

// ---------------- K4: d_p + softplus loss accumulation --------------------
// wave per sample, loops 16 samples; reduces the NSPLIT minval partials.
__global__ __launch_bounds__(256) void k_loss(const float* __restrict__ feat,
                                              const int* __restrict__ labels,
                                              const float* __restrict__ inv_norm,
                                              const float* __restrict__ sums_tot,
                                              const float* __restrict__ counts,
                                              const float* __restrict__ minval,
                                              const int* __restrict__ epoch,
                                              float* __restrict__ accum) {
    const int wave = threadIdx.x >> 6, lane = threadIdx.x & 63;
    const int base = (blockIdx.x * 4 + wave) * 16;
    const float temp = fminf(0.3f + 0.02f * (float)(*epoch), 1.0f);
    float wsum = 0.0f, wcnt = 0.0f;
    for (int s = 0; s < 16; ++s) {
        const int i = base + s;
        const int l = labels[i];
        const float cnt = counts[l];
        const float inv = inv_norm[i];
        const float4 fv = ((const float4*)(feat + (size_t)i * Dn))[lane];
        const float4 sv = ((const float4*)(sums_tot + (size_t)l * Dn))[lane];
        const float idenom = 1.0f / fmaxf(cnt - 1.0f, 1.0f);
        const float fx = fv.x * inv, fy = fv.y * inv, fz = fv.z * inv, fw = fv.w * inv;
        const float dx = fx - (sv.x - fx) * idenom;
        const float dy = fy - (sv.y - fy) * idenom;
        const float dz = fz - (sv.z - fz) * idenom;
        const float dw = fw - (sv.w - fw) * idenom;
        float ss = dx * dx + dy * dy + dz * dz + dw * dw;
        #pragma unroll
        for (int off = 1; off < 64; off <<= 1) ss += __shfl_xor(ss, off, 64);
        const float d_p = sqrtf(ss + EPSF);
        float m = minval[i];
        #pragma unroll
        for (int k = 1; k < NSPLIT; ++k) m = fminf(m, minval[(size_t)k * Bn + i]);
        const bool finite = (m < 1e37f);
        const float d_n = finite ? sqrtf(fmaxf(1.0f + m, EPSF)) : 0.0f;
        const bool valid = (cnt > 1.0f) && finite;
        if (valid) {
            const float x = (d_p - d_n) / temp;
            wsum += fmaxf(x, 0.0f) + log1pf(expf(-fabsf(x)));   // softplus
            wcnt += 1.0f;
        }
    }
    if (lane == 0) {
        atomicAdd(&accum[0], wsum);
        atomicAdd(&accum[1], wcnt);
    }
}

// ---------------- K5: finalize --------------------------------------------
__global__ void k_final(const float* __restrict__ accum, float* __restrict__ out) {
    const float s = accum[0], c = accum[1];
    out[0] = (c > 0.0f) ? (s / fmaxf(c, 1.0f)) : 0.0f;   // WEIGHT = 1.0
}

// ---------------- launch ---------------------------------------------------
extern "C" void kernel_launch(void* const* d_in, const int* in_sizes, int n_in,
                              void* d_out, int out_size, void* d_ws, size_t ws_size,
                              hipStream_t stream) {
    const float* feat  = (const float*)d_in[0];
    const int* labels  = (const int*)d_in[1];
    const int* epoch   = (const int*)d_in[2];
    float* out = (float*)d_out;
    char* ws = (char*)d_ws;

    // workspace layout (bytes)
    size_t off = 0;
    float*  sums_part = (float*)(ws + off); off += (size_t)NPART * Cn * Dn * 4; // 16 MiB
    __bf16* fnorm     = (__bf16*)(ws + off); off += (size_t)Bn * Dn * 2;        // 16 MiB
    float*  sums_tot  = (float*)(ws + off); off += (size_t)Cn * Dn * 4;         //  2 MiB
    __bf16* cent_bf   = (__bf16*)(ws + off); off += (size_t)Cn * Dn * 2;        //  1 MiB
    float*  inv_norm  = (float*)(ws + off); off += (size_t)Bn * 4;              // 128 KiB
    float*  counts    = (float*)(ws + off); off += (size_t)Cn * 4;              //   8 KiB
    float*  cn2x      = (float*)(ws + off); off += (size_t)Cn * 4;              //   8 KiB
    float*  minval    = (float*)(ws + off); off += (size_t)NSPLIT * Bn * 4;     //   1 MiB
    float*  accum     = (float*)(ws + off); off += 2 * 4;

    (void)hipMemsetAsync(sums_part, 0, (size_t)NPART * Cn * Dn * sizeof(float), stream);
    (void)hipMemsetAsync(counts,    0, (size_t)Cn * sizeof(float), stream);
    (void)hipMemsetAsync(accum,     0, 2 * sizeof(float), stream);

    k_prep<<<Bn / 4, 256, 0, stream>>>(feat, labels, sums_part, counts, inv_norm, fnorm);
    k_centroid<<<Cn / 4, 256, 0, stream>>>(sums_part, counts, sums_tot, cent_bf, cn2x);
    dim3 g3(Bn / 128, NSPLIT);
    k_main<<<g3, 256, 0, stream>>>(fnorm, labels, cent_bf, cn2x, minval);
    k_loss<<<Bn / 64, 256, 0, stream>>>(feat, labels, inv_norm, sums_tot, counts, minval,
                                        epoch, accum);
    k_final<<<1, 1, 0, stream>>>(accum, out);
}

// Round 3
// 202.789 us; speedup vs baseline: 2.0941x; 1.9780x over previous
//
#include <hip/hip_runtime.h>
#include <hip/hip_bf16.h>
#include <math.h>

// Problem constants (fixed by the reference)
constexpr int Bn = 32768;   // batch
constexpr int Dn = 256;     // embedding dim
constexpr int Cn = 2048;    // classes
constexpr int NSPLIT = 4;               // class splits in k_main
constexpr int CLS_PER_BLK = Cn / NSPLIT; // 512
constexpr int NIT = CLS_PER_BLK / 16;    // 32 class-tiles per block
#define EPSF 1e-12f
#define INFF __builtin_inff()

typedef __bf16 bf16x8 __attribute__((ext_vector_type(8)));
typedef __bf16 bf16x4 __attribute__((ext_vector_type(4)));
typedef float  f32x4  __attribute__((ext_vector_type(4)));

__device__ inline void async_copy16(const void* g, void* l) {
    __builtin_amdgcn_global_load_lds(
        (const __attribute__((address_space(1))) void*)g,
        (__attribute__((address_space(3))) void*)l, 16, 0, 0);
}

// ---------------- K1: normalize, prescale by -2, store bf16 ---------------
// wave per sample; lane covers 4 dims. fneg[i] = -2 * f_i (bf16).
__global__ __launch_bounds__(256) void k_prep(const float* __restrict__ feat,
                                              __bf16* __restrict__ fneg) {
    const int wave = threadIdx.x >> 6, lane = threadIdx.x & 63;
    const int s = blockIdx.x * 4 + wave;
    const float4 v = ((const float4*)(feat + (size_t)s * Dn))[lane];
    float ss = v.x * v.x + v.y * v.y + v.z * v.z + v.w * v.w;
    #pragma unroll
    for (int off = 1; off < 64; off <<= 1) ss += __shfl_xor(ss, off, 64);
    const float inv = -2.0f / fmaxf(sqrtf(ss), EPSF);
    bf16x4 bf;
    bf[0] = (__bf16)(v.x * inv); bf[1] = (__bf16)(v.y * inv);
    bf[2] = (__bf16)(v.z * inv); bf[3] = (__bf16)(v.w * inv);
    *(bf16x4*)(fneg + (size_t)s * Dn + lane * 4) = bf;
}

// ---------------- K2: histogram + exclusive scan (single block) -----------
__global__ __launch_bounds__(256) void k_hist(const int* __restrict__ labels,
                                              int* __restrict__ cnt_i,
                                              int* __restrict__ offs,
                                              int* __restrict__ offs_work) {
    __shared__ int hist[Cn];
    __shared__ int part[256];
    const int t = threadIdx.x;
    for (int c = t; c < Cn; c += 256) hist[c] = 0;
    __syncthreads();
    for (int i = t; i < Bn; i += 256) atomicAdd(&hist[labels[i]], 1);
    __syncthreads();
    int h[8], pre[8]; int sum = 0;
    #pragma unroll
    for (int j = 0; j < 8; ++j) { h[j] = hist[t * 8 + j]; pre[j] = sum; sum += h[j]; }
    int v = sum;
    part[t] = v; __syncthreads();
    for (int off = 1; off < 256; off <<= 1) {
        int add = (t >= off) ? part[t - off] : 0;
        __syncthreads();
        v += add; part[t] = v;
        __syncthreads();
    }
    const int base = v - sum;   // exclusive prefix of this thread's 8 bins
    #pragma unroll
    for (int j = 0; j < 8; ++j) {
        const int b = t * 8 + j, o = base + pre[j];
        cnt_i[b] = h[j]; offs[b] = o; offs_work[b] = o;
    }
}

// ---------------- K3: scatter sample indices by class ---------------------
__global__ __launch_bounds__(256) void k_scatter(const int* __restrict__ labels,
                                                 int* __restrict__ offs_work,
                                                 int* __restrict__ order) {
    const int i = blockIdx.x * 256 + threadIdx.x;
    const int pos = atomicAdd(&offs_work[labels[i]], 1);
    order[pos] = i;
}

// ---------------- K4: per-class sums -> centK (K-major bf16), cn2, d_p ----
// wave per class; lane covers 4 dims. fneg holds -2f; scale by -0.5.
__global__ __launch_bounds__(256) void k_centseg(const __bf16* __restrict__ fneg,
                                                 const int* __restrict__ order,
                                                 const int* __restrict__ offs,
                                                 const int* __restrict__ cnt_i,
                                                 __bf16* __restrict__ centK,
                                                 float* __restrict__ cn2x,
                                                 float* __restrict__ d_p) {
    const int wave = threadIdx.x >> 6, lane = threadIdx.x & 63;
    const int c = blockIdx.x * 4 + wave;
    const int n = cnt_i[c], start = offs[c];
    // pre-load member indices: lane j holds order[start+j] (n <= 64 fast path)
    int myidx = 0;
    if (lane < n) myidx = order[start + lane];
    float sx = 0.f, sy = 0.f, sz = 0.f, sw = 0.f;
    const int nf = (n < 64) ? n : 64;
    for (int j = 0; j < nf; ++j) {
        const int idx = __shfl(myidx, j, 64);
        const bf16x4 v = *(const bf16x4*)(fneg + (size_t)idx * Dn + lane * 4);
        sx += -0.5f * (float)v[0]; sy += -0.5f * (float)v[1];
        sz += -0.5f * (float)v[2]; sw += -0.5f * (float)v[3];
    }
    for (int j = 64; j < n; ++j) {          // overflow fallback (rare)
        const int idx = order[start + j];
        const bf16x4 v = *(const bf16x4*)(fneg + (size_t)idx * Dn + lane * 4);
        sx += -0.5f * (float)v[0]; sy += -0.5f * (float)v[1];
        sz += -0.5f * (float)v[2]; sw += -0.5f * (float)v[3];
    }
    const float invn = 1.0f / fmaxf((float)n, 1.0f);
    const float cx = sx * invn, cy = sy * invn, cz = sz * invn, cw = sw * invn;
    // centK chunk (kc, c): dims [8kc, 8kc+8); lane covers kc = lane>>1, half lane&1
    bf16x4 cb; cb[0] = (__bf16)cx; cb[1] = (__bf16)cy; cb[2] = (__bf16)cz; cb[3] = (__bf16)cw;
    *(bf16x4*)(centK + ((size_t)(lane >> 1) * Cn + c) * 8 + (lane & 1) * 4) = cb;
    float ss = cx * cx + cy * cy + cz * cz + cw * cw;
    #pragma unroll
    for (int off = 1; off < 64; off <<= 1) ss += __shfl_xor(ss, off, 64);
    ss = __shfl(ss, 0, 64);
    if (lane == 0) cn2x[c] = (n > 0) ? ss : INFF;
    // pass 2: leave-one-out d_p for each member
    const float inm = 1.0f / fmaxf((float)(n - 1), 1.0f);
    const float am = 1.0f + inm;
    const float bx = sx * inm, by = sy * inm, bz = sz * inm, bw = sw * inm;
    for (int j = 0; j < n; ++j) {
        const int idx = (j < 64) ? __shfl(myidx, j, 64) : order[start + j];
        const bf16x4 v = *(const bf16x4*)(fneg + (size_t)idx * Dn + lane * 4);
        const float fx = -0.5f * (float)v[0], fy = -0.5f * (float)v[1];
        const float fz = -0.5f * (float)v[2], fw = -0.5f * (float)v[3];
        const float dx = fx * am - bx, dy = fy * am - by;
        const float dz = fz * am - bz, dw = fw * am - bw;
        float s4 = dx * dx + dy * dy + dz * dz + dw * dw;
        #pragma unroll
        for (int off = 1; off < 64; off <<= 1) s4 += __shfl_xor(s4, off, 64);
        if (lane == 0) d_p[idx] = sqrtf(s4 + EPSF);
    }
}

// ---------------- K5: MFMA dot + masked min (LDS-staged B, dbuf) ----------
// grid (Bn/256, NSPLIT); block 256 = 4 waves; wave owns 64 samples (4 tiles).
// A = -2f (prescaled), so s = cn2 + acc = cn2 - 2*dot = d^2 - 1.
__global__ __launch_bounds__(256, 2) void k_main(const __bf16* __restrict__ fneg,
                                                 const int* __restrict__ labels,
                                                 const __bf16* __restrict__ centK,
                                                 const float* __restrict__ cn2x,
                                                 float* __restrict__ minval) {
    __shared__ __align__(16) __bf16 sB[2][16 * Dn];   // 2 x 8KB class tiles
    const int lane = threadIdx.x & 63, wave = threadIdx.x >> 6;
    const int m16 = lane & 15, quad = lane >> 4;
    const int sbase = blockIdx.x * 256 + wave * 64;
    const int c_begin = blockIdx.y * CLS_PER_BLK;

    // A fragments: a[p][t] = fneg[sbase+16p+m16][32t+8*quad .. +7]
    bf16x8 a[4][8];
    #pragma unroll
    for (int p = 0; p < 4; ++p) {
        const __bf16* fr = fneg + (size_t)(sbase + p * 16 + m16) * Dn + quad * 8;
        #pragma unroll
        for (int t = 0; t < 8; ++t) a[p][t] = *(const bf16x8*)(fr + t * 32);
    }
    int lab[4][4];
    #pragma unroll
    for (int p = 0; p < 4; ++p)
        #pragma unroll
        for (int r = 0; r < 4; ++r)
            lab[p][r] = labels[sbase + p * 16 + quad * 4 + r];

    float rm[4][4];
    #pragma unroll
    for (int p = 0; p < 4; ++p)
        #pragma unroll
        for (int r = 0; r < 4; ++r) rm[p][r] = INFF;

    // stage class-tile `it` into sB[buf]: chunk ch = kc*16+n at LDS addr ch*16B
    auto stage = [&](int buf, int it) {
        const int c0 = c_begin + it * 16;
        #pragma unroll
        for (int j = 0; j < 2; ++j) {
            const int chunk = wave * 128 + j * 64 + lane;     // 0..511
            const int kc = chunk >> 4, n = chunk & 15;
            const __bf16* g = centK + ((size_t)kc * Cn + (c0 + n)) * 8;
            __bf16* l = &sB[buf][(size_t)(wave * 128 + j * 64) * 8]; // wave-uniform
            async_copy16(g, l);
        }
    };

    stage(0, 0);
    __syncthreads();
    for (int it = 0; it < NIT; ++it) {
        const int cur = it & 1;
        if (it + 1 < NIT) stage(cur ^ 1, it + 1);
        const int c0 = c_begin + it * 16;
        const float cn2v = cn2x[c0 + m16];
        bf16x8 b[8];
        const __bf16* ls = &sB[cur][0];
        #pragma unroll
        for (int t = 0; t < 8; ++t)
            b[t] = *(const bf16x8*)(ls + t * 512 + lane * 8);  // lane-linear: conflict-free
        f32x4 acc[4] = {{0.f,0.f,0.f,0.f},{0.f,0.f,0.f,0.f},
                        {0.f,0.f,0.f,0.f},{0.f,0.f,0.f,0.f}};
        #pragma unroll
        for (int t = 0; t < 8; ++t)
            #pragma unroll
            for (int p = 0; p < 4; ++p)
                acc[p] = __builtin_amdgcn_mfma_f32_16x16x32_bf16(a[p][t], b[t], acc[p], 0, 0, 0);
        const int crow = c0 + m16;
        #pragma unroll
        for (int p = 0; p < 4; ++p)
            #pragma unroll
            for (int r = 0; r < 4; ++r) {
                const float sel = (crow == lab[p][r]) ? INFF : cn2v;
                rm[p][r] = fminf(rm[p][r], sel + acc[p][r]);
            }
        __syncthreads();
    }
    #pragma unroll
    for (int off = 1; off < 16; off <<= 1)
        #pragma unroll
        for (int p = 0; p < 4; ++p)
            #pragma unroll
            for (int r = 0; r < 4; ++r)
                rm[p][r] = fminf(rm[p][r], __shfl_xor(rm[p][r], off, 64));
    if (m16 == 0) {
        float* mv = minval + (size_t)blockIdx.y * Bn;
        #pragma unroll
        for (int p = 0; p < 4; ++p)
            #pragma unroll
            for (int r = 0; r < 4; ++r)
                mv[sbase + p * 16 + quad * 4 + r] = rm[p][r];
    }
}

// ---------------- K6: softplus loss accumulation --------------------------
__global__ __launch_bounds__(256) void k_final(const int* __restrict__ labels,
                                               const int* __restrict__ cnt_i,
                                               const float* __restrict__ d_p,
                                               const float* __restrict__ minval,
                                               const int* __restrict__ epoch,
                                               float* __restrict__ accum) {
    const int i = blockIdx.x * 256 + threadIdx.x;
    const int lane = threadIdx.x & 63;
    const float temp = fminf(0.3f + 0.02f * (float)(*epoch), 1.0f);
    float m = minval[i];
    #pragma unroll
    for (int k = 1; k < NSPLIT; ++k) m = fminf(m, minval[(size_t)k * Bn + i]);
    const bool finite = (m < 1e37f);
    const float d_n = finite ? sqrtf(fmaxf(1.0f + m, EPSF)) : 0.0f;
    const bool valid = (cnt_i[labels[i]] > 1) && finite;
    const float x = (d_p[i] - d_n) / temp;
    const float sp = fmaxf(x, 0.0f) + log1pf(expf(-fabsf(x)));
    float ws = valid ? sp : 0.0f, wc = valid ? 1.0f : 0.0f;
    #pragma unroll
    for (int off = 1; off < 64; off <<= 1) {
        ws += __shfl_xor(ws, off, 64);
        wc += __shfl_xor(wc, off, 64);
    }
    if (lane == 0) {
        atomicAdd(&accum[0], ws);
        atomicAdd(&accum[1], wc);
    }
}

// ---------------- K7: finalize --------------------------------------------
__global__ void k_out(const float* __restrict__ accum, float* __restrict__ out) {
    const float s = accum[0], c = accum[1];
    out[0] = (c > 0.0f) ? (s / fmaxf(c, 1.0f)) : 0.0f;   // WEIGHT = 1.0
}

// ---------------- launch ---------------------------------------------------
extern "C" void kernel_launch(void* const* d_in, const int* in_sizes, int n_in,
                              void* d_out, int out_size, void* d_ws, size_t ws_size,
                              hipStream_t stream) {
    const float* feat  = (const float*)d_in[0];
    const int* labels  = (const int*)d_in[1];
    const int* epoch   = (const int*)d_in[2];
    float* out = (float*)d_out;
    char* ws = (char*)d_ws;

    size_t off = 0;
    __bf16* fneg     = (__bf16*)(ws + off); off += (size_t)Bn * Dn * 2;     // 16 MiB
    __bf16* centK    = (__bf16*)(ws + off); off += (size_t)Cn * Dn * 2;     //  1 MiB
    float*  cn2x     = (float*)(ws + off);  off += (size_t)Cn * 4;
    int*    cnt_i    = (int*)(ws + off);    off += (size_t)Cn * 4;
    int*    offs     = (int*)(ws + off);    off += (size_t)Cn * 4;
    int*    offs_wk  = (int*)(ws + off);    off += (size_t)Cn * 4;
    int*    order    = (int*)(ws + off);    off += (size_t)Bn * 4;
    float*  d_p      = (float*)(ws + off);  off += (size_t)Bn * 4;
    float*  minval   = (float*)(ws + off);  off += (size_t)NSPLIT * Bn * 4;
    float*  accum    = (float*)(ws + off);  off += 2 * 4;

    (void)hipMemsetAsync(accum, 0, 2 * sizeof(float), stream);

    k_prep<<<Bn / 4, 256, 0, stream>>>(feat, fneg);
    k_hist<<<1, 256, 0, stream>>>(labels, cnt_i, offs, offs_wk);
    k_scatter<<<Bn / 256, 256, 0, stream>>>(labels, offs_wk, order);
    k_centseg<<<Cn / 4, 256, 0, stream>>>(fneg, order, offs, cnt_i, centK, cn2x, d_p);
    dim3 g5(Bn / 256, NSPLIT);
    k_main<<<g5, 256, 0, stream>>>(fneg, labels, centK, cn2x, minval);
    k_final<<<Bn / 256, 256, 0, stream>>>(labels, cnt_i, d_p, minval, epoch, accum);
    k_out<<<1, 1, 0, stream>>>(accum, out);
}

// Round 4
// 166.166 us; speedup vs baseline: 2.5556x; 1.2204x over previous
//
#include <hip/hip_runtime.h>
#include <hip/hip_bf16.h>
#include <math.h>

// Problem constants (fixed by the reference)
constexpr int Bn = 32768;   // batch
constexpr int Dn = 256;     // embedding dim
constexpr int Cn = 2048;    // classes
constexpr int NSPLIT = 4;               // class splits in k_main
constexpr int CLS_PER_BLK = Cn / NSPLIT; // 512
constexpr int NIT = CLS_PER_BLK / 16;    // 32 class-tiles per block
#define EPSF 1e-12f
#define INFF __builtin_inff()

typedef __bf16 bf16x8 __attribute__((ext_vector_type(8)));
typedef __bf16 bf16x4 __attribute__((ext_vector_type(4)));
typedef float  f32x4  __attribute__((ext_vector_type(4)));

__device__ inline void async_copy16(const void* g, void* l) {
    __builtin_amdgcn_global_load_lds(
        (const __attribute__((address_space(1))) void*)g,
        (__attribute__((address_space(3))) void*)l, 16, 0, 0);
}

// ---------------- K1: normalize, prescale by -2, store bf16; + histogram --
// wave per sample; lane covers 4 dims. fneg[i] = -2 * f_i (bf16).
__global__ __launch_bounds__(256) void k_prep(const float* __restrict__ feat,
                                              const int* __restrict__ labels,
                                              __bf16* __restrict__ fneg,
                                              int* __restrict__ hist) {
    const int wave = threadIdx.x >> 6, lane = threadIdx.x & 63;
    const int s = blockIdx.x * 4 + wave;
    const float4 v = ((const float4*)(feat + (size_t)s * Dn))[lane];
    float ss = v.x * v.x + v.y * v.y + v.z * v.z + v.w * v.w;
    #pragma unroll
    for (int off = 1; off < 64; off <<= 1) ss += __shfl_xor(ss, off, 64);
    const float inv = -2.0f / fmaxf(sqrtf(ss), EPSF);
    bf16x4 bf;
    bf[0] = (__bf16)(v.x * inv); bf[1] = (__bf16)(v.y * inv);
    bf[2] = (__bf16)(v.z * inv); bf[3] = (__bf16)(v.w * inv);
    *(bf16x4*)(fneg + (size_t)s * Dn + lane * 4) = bf;
    if (lane == 0) atomicAdd(&hist[labels[s]], 1);
}

// ---------------- K2: exclusive scan of 2048-bin histogram (1 tiny block) -
__global__ __launch_bounds__(256) void k_scan(const int* __restrict__ hist,
                                              int* __restrict__ cnt_i,
                                              int* __restrict__ offs,
                                              int* __restrict__ offs_work) {
    __shared__ int part[256];
    const int t = threadIdx.x;
    int h[8], pre[8]; int sum = 0;
    #pragma unroll
    for (int j = 0; j < 8; ++j) { h[j] = hist[t * 8 + j]; pre[j] = sum; sum += h[j]; }
    int v = sum;
    part[t] = v; __syncthreads();
    for (int off = 1; off < 256; off <<= 1) {
        int add = (t >= off) ? part[t - off] : 0;
        __syncthreads();
        v += add; part[t] = v;
        __syncthreads();
    }
    const int base = v - sum;   // exclusive prefix of this thread's 8 bins
    #pragma unroll
    for (int j = 0; j < 8; ++j) {
        const int b = t * 8 + j, o = base + pre[j];
        cnt_i[b] = h[j]; offs[b] = o; offs_work[b] = o;
    }
}

// ---------------- K3: scatter sample indices by class ---------------------
__global__ __launch_bounds__(256) void k_scatter(const int* __restrict__ labels,
                                                 int* __restrict__ offs_work,
                                                 int* __restrict__ order) {
    const int i = blockIdx.x * 256 + threadIdx.x;
    const int pos = atomicAdd(&offs_work[labels[i]], 1);
    order[pos] = i;
}

// ---------------- K4: per-class sums -> centK (K-major bf16) + cn2 --------
// wave per class; lane covers 4 dims. fneg holds -2f; scale by -0.5.
__global__ __launch_bounds__(256) void k_centseg(const __bf16* __restrict__ fneg,
                                                 const int* __restrict__ order,
                                                 const int* __restrict__ offs,
                                                 const int* __restrict__ cnt_i,
                                                 __bf16* __restrict__ centK,
                                                 float* __restrict__ cn2x) {
    const int wave = threadIdx.x >> 6, lane = threadIdx.x & 63;
    const int c = blockIdx.x * 4 + wave;
    const int n = cnt_i[c], start = offs[c];
    int myidx = 0;
    if (lane < n) myidx = order[start + lane];
    float sx = 0.f, sy = 0.f, sz = 0.f, sw = 0.f;
    const int nf = (n < 64) ? n : 64;
    for (int j = 0; j < nf; ++j) {
        const int idx = __shfl(myidx, j, 64);
        const bf16x4 v = *(const bf16x4*)(fneg + (size_t)idx * Dn + lane * 4);
        sx += -0.5f * (float)v[0]; sy += -0.5f * (float)v[1];
        sz += -0.5f * (float)v[2]; sw += -0.5f * (float)v[3];
    }
    for (int j = 64; j < n; ++j) {          // overflow fallback (rare)
        const int idx = order[start + j];
        const bf16x4 v = *(const bf16x4*)(fneg + (size_t)idx * Dn + lane * 4);
        sx += -0.5f * (float)v[0]; sy += -0.5f * (float)v[1];
        sz += -0.5f * (float)v[2]; sw += -0.5f * (float)v[3];
    }
    const float invn = 1.0f / fmaxf((float)n, 1.0f);
    const float cx = sx * invn, cy = sy * invn, cz = sz * invn, cw = sw * invn;
    // centK chunk (kc, c): dims [8kc, 8kc+8); lane covers kc = lane>>1, half lane&1
    bf16x4 cb; cb[0] = (__bf16)cx; cb[1] = (__bf16)cy; cb[2] = (__bf16)cz; cb[3] = (__bf16)cw;
    *(bf16x4*)(centK + ((size_t)(lane >> 1) * Cn + c) * 8 + (lane & 1) * 4) = cb;
    float ss = cx * cx + cy * cy + cz * cz + cw * cw;
    #pragma unroll
    for (int off = 1; off < 64; off <<= 1) ss += __shfl_xor(ss, off, 64);
    if (lane == 0) cn2x[c] = (n > 0) ? ss : INFF;
}

// ---------------- K5: MFMA dot + masked min + own-class dot extraction ----
// grid (Bn/256, NSPLIT); block 256 = 4 waves; wave owns 64 samples (4 tiles).
// A = -2f (prescaled), so cn2 + acc = cn2 - 2*dot = d^2 - 1.
__global__ __launch_bounds__(256, 2) void k_main(const __bf16* __restrict__ fneg,
                                                 const int* __restrict__ labels,
                                                 const __bf16* __restrict__ centK,
                                                 const float* __restrict__ cn2x,
                                                 float* __restrict__ minval,
                                                 float* __restrict__ dotown) {
    __shared__ __align__(16) __bf16 sB[2][16 * Dn];   // 2 x 8KB class tiles
    __shared__ float s_cn2[CLS_PER_BLK];               // 2KB
    const int lane = threadIdx.x & 63, wave = threadIdx.x >> 6;
    const int m16 = lane & 15, quad = lane >> 4;
    const int sbase = blockIdx.x * 256 + wave * 64;
    const int c_begin = blockIdx.y * CLS_PER_BLK;

    // A fragments: a[p][t] = fneg[sbase+16p+m16][32t+8*quad .. +7]
    bf16x8 a[4][8];
    #pragma unroll
    for (int p = 0; p < 4; ++p) {
        const __bf16* fr = fneg + (size_t)(sbase + p * 16 + m16) * Dn + quad * 8;
        #pragma unroll
        for (int t = 0; t < 8; ++t) a[p][t] = *(const bf16x8*)(fr + t * 32);
    }
    int lab[4][4];
    #pragma unroll
    for (int p = 0; p < 4; ++p)
        #pragma unroll
        for (int r = 0; r < 4; ++r)
            lab[p][r] = labels[sbase + p * 16 + quad * 4 + r];

    float rm[4][4], dacc[4][4];
    #pragma unroll
    for (int p = 0; p < 4; ++p)
        #pragma unroll
        for (int r = 0; r < 4; ++r) { rm[p][r] = INFF; dacc[p][r] = 0.0f; }

    // stage class-tile `it` into sB[buf]: chunk ch = kc*16+n at LDS addr ch*16B
    auto stage = [&](int buf, int it) {
        const int c0 = c_begin + it * 16;
        #pragma unroll
        for (int j = 0; j < 2; ++j) {
            const int chunk = wave * 128 + j * 64 + lane;     // 0..511
            const int kc = chunk >> 4, n = chunk & 15;
            const __bf16* g = centK + ((size_t)kc * Cn + (c0 + n)) * 8;
            __bf16* l = &sB[buf][(size_t)(wave * 128 + j * 64) * 8]; // wave-uniform
            async_copy16(g, l);
        }
    };

    stage(0, 0);
    for (int c = threadIdx.x; c < CLS_PER_BLK; c += 256) s_cn2[c] = cn2x[c_begin + c];
    __syncthreads();
    for (int it = 0; it < NIT; ++it) {
        const int cur = it & 1;
        if (it + 1 < NIT) stage(cur ^ 1, it + 1);
        const float cn2v = s_cn2[it * 16 + m16];
        const __bf16* ls = &sB[cur][0];
        f32x4 acc[4] = {{0.f,0.f,0.f,0.f},{0.f,0.f,0.f,0.f},
                        {0.f,0.f,0.f,0.f},{0.f,0.f,0.f,0.f}};
        #pragma unroll
        for (int t = 0; t < 8; ++t) {
            const bf16x8 b = *(const bf16x8*)(ls + t * 512 + lane * 8); // conflict-free
            #pragma unroll
            for (int p = 0; p < 4; ++p)
                acc[p] = __builtin_amdgcn_mfma_f32_16x16x32_bf16(a[p][t], b, acc[p], 0, 0, 0);
        }
        const int crow = c_begin + it * 16 + m16;
        #pragma unroll
        for (int p = 0; p < 4; ++p)
            #pragma unroll
            for (int r = 0; r < 4; ++r) {
                const bool own = (crow == lab[p][r]);
                const float sel = own ? INFF : cn2v;
                rm[p][r] = fminf(rm[p][r], sel + acc[p][r]);
                dacc[p][r] += own ? acc[p][r] : 0.0f;
            }
        __syncthreads();
    }
    #pragma unroll
    for (int off = 1; off < 16; off <<= 1)
        #pragma unroll
        for (int p = 0; p < 4; ++p)
            #pragma unroll
            for (int r = 0; r < 4; ++r) {
                rm[p][r] = fminf(rm[p][r], __shfl_xor(rm[p][r], off, 64));
                dacc[p][r] += __shfl_xor(dacc[p][r], off, 64);
            }
    if (m16 == 0) {
        float* mv = minval + (size_t)blockIdx.y * Bn;
        float* dv = dotown + (size_t)blockIdx.y * Bn;
        #pragma unroll
        for (int p = 0; p < 4; ++p)
            #pragma unroll
            for (int r = 0; r < 4; ++r) {
                mv[sbase + p * 16 + quad * 4 + r] = rm[p][r];
                dv[sbase + p * 16 + quad * 4 + r] = dacc[p][r];
            }
    }
}

// ---------------- K6: d_p (from own-class dot), d_n, softplus, reduce -----
__global__ __launch_bounds__(256) void k_final(const int* __restrict__ labels,
                                               const int* __restrict__ cnt_i,
                                               const float* __restrict__ cn2x,
                                               const float* __restrict__ minval,
                                               const float* __restrict__ dotown,
                                               const int* __restrict__ epoch,
                                               float* __restrict__ accum) {
    const int i = blockIdx.x * 256 + threadIdx.x;
    const int lane = threadIdx.x & 63;
    const float temp = fminf(0.3f + 0.02f * (float)(*epoch), 1.0f);
    float m = minval[i];
    float draw = dotown[i];                 // = -2 * f.c_own (one split nonzero)
    #pragma unroll
    for (int k = 1; k < NSPLIT; ++k) {
        m = fminf(m, minval[(size_t)k * Bn + i]);
        draw += dotown[(size_t)k * Bn + i];
    }
    const int l = labels[i];
    const int n = cnt_i[l];
    const float nf = (float)n;
    const float cn2 = cn2x[l];              // finite (n >= 1)
    // d_p from ||f||^2=1, f.s = n*f.c, ||s||^2 = n^2*cn2:
    const float fds = nf * (-0.5f * draw);
    const float fm1 = fmaxf(nf - 1.0f, 1.0f);
    const float fdcp = (fds - 1.0f) / fm1;
    const float cp2 = (nf * nf * cn2 - 2.0f * fds + 1.0f) / (fm1 * fm1);
    const float dp2 = 1.0f - 2.0f * fdcp + cp2;
    const float d_p = sqrtf(fmaxf(dp2, 0.0f) + EPSF);
    const bool finite = (m < 1e37f);
    const float d_n = finite ? sqrtf(fmaxf(1.0f + m, EPSF)) : 0.0f;
    const bool valid = (n > 1) && finite;
    const float x = (d_p - d_n) / temp;
    const float sp = fmaxf(x, 0.0f) + log1pf(expf(-fabsf(x)));
    float ws = valid ? sp : 0.0f, wc = valid ? 1.0f : 0.0f;
    #pragma unroll
    for (int off = 1; off < 64; off <<= 1) {
        ws += __shfl_xor(ws, off, 64);
        wc += __shfl_xor(wc, off, 64);
    }
    if (lane == 0) {
        atomicAdd(&accum[0], ws);
        atomicAdd(&accum[1], wc);
    }
}

// ---------------- K7: finalize --------------------------------------------
__global__ void k_out(const float* __restrict__ accum, float* __restrict__ out) {
    const float s = accum[0], c = accum[1];
    out[0] = (c > 0.0f) ? (s / fmaxf(c, 1.0f)) : 0.0f;   // WEIGHT = 1.0
}

// ---------------- launch ---------------------------------------------------
extern "C" void kernel_launch(void* const* d_in, const int* in_sizes, int n_in,
                              void* d_out, int out_size, void* d_ws, size_t ws_size,
                              hipStream_t stream) {
    const float* feat  = (const float*)d_in[0];
    const int* labels  = (const int*)d_in[1];
    const int* epoch   = (const int*)d_in[2];
    float* out = (float*)d_out;
    char* ws = (char*)d_ws;

    size_t off = 0;
    __bf16* fneg     = (__bf16*)(ws + off); off += (size_t)Bn * Dn * 2;     // 16 MiB
    __bf16* centK    = (__bf16*)(ws + off); off += (size_t)Cn * Dn * 2;     //  1 MiB
    float*  cn2x     = (float*)(ws + off);  off += (size_t)Cn * 4;
    int*    hist     = (int*)(ws + off);    off += (size_t)Cn * 4;
    int*    cnt_i    = (int*)(ws + off);    off += (size_t)Cn * 4;
    int*    offs     = (int*)(ws + off);    off += (size_t)Cn * 4;
    int*    offs_wk  = (int*)(ws + off);    off += (size_t)Cn * 4;
    int*    order    = (int*)(ws + off);    off += (size_t)Bn * 4;
    float*  minval   = (float*)(ws + off);  off += (size_t)NSPLIT * Bn * 4;
    float*  dotown   = (float*)(ws + off);  off += (size_t)NSPLIT * Bn * 4;
    float*  accum    = (float*)(ws + off);  off += 2 * 4;

    (void)hipMemsetAsync(hist,  0, (size_t)Cn * sizeof(int), stream);
    (void)hipMemsetAsync(accum, 0, 2 * sizeof(float), stream);

    k_prep<<<Bn / 4, 256, 0, stream>>>(feat, labels, fneg, hist);
    k_scan<<<1, 256, 0, stream>>>(hist, cnt_i, offs, offs_wk);
    k_scatter<<<Bn / 256, 256, 0, stream>>>(labels, offs_wk, order);
    k_centseg<<<Cn / 4, 256, 0, stream>>>(fneg, order, offs, cnt_i, centK, cn2x);
    dim3 g5(Bn / 256, NSPLIT);
    k_main<<<g5, 256, 0, stream>>>(fneg, labels, centK, cn2x, minval, dotown);
    k_final<<<Bn / 256, 256, 0, stream>>>(labels, cnt_i, cn2x, minval, dotown,
                                          epoch, accum);
    k_out<<<1, 1, 0, stream>>>(accum, out);
}